// Round 1
// baseline (108.565 us; speedup 1.0000x reference)
//
#include <hip/hip_runtime.h>

typedef short short8 __attribute__((ext_vector_type(8)));
typedef float floatx4 __attribute__((ext_vector_type(4)));

#define NEG_SLOPE 0.2f

// bf16 round-to-nearest-even via bit manipulation (inputs finite)
__device__ __forceinline__ unsigned short f2b(float x) {
    unsigned u = __float_as_uint(x);
    u += 0x7fffu + ((u >> 16) & 1u);
    return (unsigned short)(u >> 16);
}
__device__ __forceinline__ float b2f(unsigned short s) {
    return __uint_as_float(((unsigned)s) << 16);
}
__device__ __forceinline__ void cvt4(float4 v, ushort4& hi, ushort4& lo) {
    hi.x = f2b(v.x); hi.y = f2b(v.y); hi.z = f2b(v.z); hi.w = f2b(v.w);
    lo.x = f2b(v.x - b2f(hi.x)); lo.y = f2b(v.y - b2f(hi.y));
    lo.z = f2b(v.z - b2f(hi.z)); lo.w = f2b(v.w - b2f(hi.w));
}

// Kernel 1: Wh = h @ W^T via split-bf16 (hi/lo, 3 MFMA passes -> ~fp32 accuracy).
// Writes WhbT[b][h][d][i] (bf16, transposed for kernel2's B-fragment loads),
// E1F1[b,h,i] = (exp(s1), exp(0.2*s1)), E2F2[b,h,j] = m_j * (exp(s2), exp(0.2*s2)).
// Block: BM=64 rows x BN=128 cols, BK=64, 4 waves in 2x2 grid (wave = 32 rows x 64 cols
// = one full head's column range, so s1/s2 reductions stay wave-local).
__global__ __launch_bounds__(256) void k_wh(
    const float* __restrict__ hin, const int* __restrict__ mask,
    const float* __restrict__ W, const float* __restrict__ a,
    unsigned short* __restrict__ WhbT, float2* __restrict__ E1F1,
    float2* __restrict__ E2F2)
{
    // pad rows to 72 bf16 (144B) -> bank rotation by 4, conflict-free
    __shared__ unsigned short Ahi[64 * 72], Alo[64 * 72];
    __shared__ unsigned short Bhi[128 * 72], Blo[128 * 72];

    const int t = threadIdx.x;
    const int bi = blockIdx.x;
    const int mb = bi & 15, cb = (bi >> 4) & 1, b = bi >> 5;
    const int m0 = mb * 64, n0 = cb * 128;
    const int wid = t >> 6, lane = t & 63;
    const int wm = wid >> 1, wn = wid & 1;
    const int l15 = lane & 15, q = lane >> 4;

    floatx4 acc[2][4];
#pragma unroll
    for (int mt = 0; mt < 2; ++mt)
#pragma unroll
        for (int nt = 0; nt < 4; ++nt) {
            floatx4 z = {0.f, 0.f, 0.f, 0.f};
            acc[mt][nt] = z;
        }

    for (int kt = 0; kt < 4; ++kt) {
        const int k0 = kt * 64;
        // stage A tile (h): 64 rows x 64 cols fp32 -> hi/lo bf16
#pragma unroll
        for (int p = 0; p < 4; ++p) {
            int idx = t + 256 * p;
            int row = idx >> 4, c4 = idx & 15;
            float4 v = *(const float4*)&hin[((size_t)(b * 1024 + m0 + row)) * 256 + k0 + c4 * 4];
            ushort4 hi, lo;
            cvt4(v, hi, lo);
            *(ushort4*)&Ahi[row * 72 + c4 * 4] = hi;
            *(ushort4*)&Alo[row * 72 + c4 * 4] = lo;
        }
        // stage B tile (W rows = output cols): 128 rows x 64 cols
#pragma unroll
        for (int p = 0; p < 8; ++p) {
            int idx = t + 256 * p;
            int row = idx >> 4, c4 = idx & 15;
            float4 v = *(const float4*)&W[((size_t)(n0 + row)) * 256 + k0 + c4 * 4];
            ushort4 hi, lo;
            cvt4(v, hi, lo);
            *(ushort4*)&Bhi[row * 72 + c4 * 4] = hi;
            *(ushort4*)&Blo[row * 72 + c4 * 4] = lo;
        }
        __syncthreads();
#pragma unroll
        for (int ks = 0; ks < 2; ++ks) {
            short8 ah[2], al[2], bh[4], bl[4];
#pragma unroll
            for (int mt = 0; mt < 2; ++mt) {
                int r = wm * 32 + mt * 16 + l15;
                ah[mt] = *(const short8*)&Ahi[r * 72 + ks * 32 + q * 8];
                al[mt] = *(const short8*)&Alo[r * 72 + ks * 32 + q * 8];
            }
#pragma unroll
            for (int nt = 0; nt < 4; ++nt) {
                int r = wn * 64 + nt * 16 + l15;
                bh[nt] = *(const short8*)&Bhi[r * 72 + ks * 32 + q * 8];
                bl[nt] = *(const short8*)&Blo[r * 72 + ks * 32 + q * 8];
            }
#pragma unroll
            for (int mt = 0; mt < 2; ++mt)
#pragma unroll
                for (int nt = 0; nt < 4; ++nt) {
                    acc[mt][nt] = __builtin_amdgcn_mfma_f32_16x16x32_bf16(ah[mt], bh[nt], acc[mt][nt], 0, 0, 0);
                    acc[mt][nt] = __builtin_amdgcn_mfma_f32_16x16x32_bf16(ah[mt], bl[nt], acc[mt][nt], 0, 0, 0);
                    acc[mt][nt] = __builtin_amdgcn_mfma_f32_16x16x32_bf16(al[mt], bh[nt], acc[mt][nt], 0, 0, 0);
                }
        }
        __syncthreads();
    }

    // ---- epilogue ----
    const int hh = cb * 2 + wn;       // head handled by this wave
    const int b4h = b * 4 + hh;

    float a1v[4], a2v[4];
#pragma unroll
    for (int nt = 0; nt < 4; ++nt) {
        a1v[nt] = a[nt * 16 + l15];
        a2v[nt] = a[64 + nt * 16 + l15];
    }

    // write WhbT (bf16, [b][h][d][i]) : 4 consecutive i per ushort4
#pragma unroll
    for (int mt = 0; mt < 2; ++mt)
#pragma unroll
        for (int nt = 0; nt < 4; ++nt) {
            int d = nt * 16 + l15;
            int i0r = m0 + wm * 32 + mt * 16 + q * 4;
            ushort4 wv;
            wv.x = f2b(acc[mt][nt][0]);
            wv.y = f2b(acc[mt][nt][1]);
            wv.z = f2b(acc[mt][nt][2]);
            wv.w = f2b(acc[mt][nt][3]);
            *(ushort4*)&WhbT[((size_t)(b4h * 64 + d)) * 1024 + i0r] = wv;
        }

    // s1/s2 per row: dot over this wave's 64 head-cols (nt x l15), butterfly over l15
    float s1p[2][4], s2p[2][4];
#pragma unroll
    for (int mt = 0; mt < 2; ++mt)
#pragma unroll
        for (int r = 0; r < 4; ++r) {
            float s1 = 0.f, s2 = 0.f;
#pragma unroll
            for (int nt = 0; nt < 4; ++nt) {
                s1 += acc[mt][nt][r] * a1v[nt];
                s2 += acc[mt][nt][r] * a2v[nt];
            }
            s1p[mt][r] = s1;
            s2p[mt][r] = s2;
        }
#pragma unroll
    for (int off = 1; off <= 8; off <<= 1)
#pragma unroll
        for (int mt = 0; mt < 2; ++mt)
#pragma unroll
            for (int r = 0; r < 4; ++r) {
                s1p[mt][r] += __shfl_xor(s1p[mt][r], off, 64);
                s2p[mt][r] += __shfl_xor(s2p[mt][r], off, 64);
            }

    if (l15 == 0) {
#pragma unroll
        for (int mt = 0; mt < 2; ++mt)
#pragma unroll
            for (int r = 0; r < 4; ++r) {
                int i = m0 + wm * 32 + mt * 16 + q * 4 + r;
                float s1 = s1p[mt][r], s2 = s2p[mt][r];
                E1F1[(size_t)b4h * 1024 + i] = make_float2(__expf(s1), __expf(NEG_SLOPE * s1));
                int mj = mask[b * 1024 + i];
                float e2 = mj ? __expf(s2) : 0.f;
                float g2 = mj ? __expf(NEG_SLOPE * s2) : 0.f;
                E2F2[(size_t)b4h * 1024 + i] = make_float2(e2, g2);
            }
    }
}

// Kernel 2: flash-style aggregation. out[i,:] = (sum_j w_ij * Wh[j,:]) / (sum_j w_ij)
// with w_ij = max(E1_i*E2_j, F1_i*F2_j) = exp(lrelu(s1_i+s2_j)) (masked j -> 0).
// Block = (b, h, 128 rows), 4 waves x 32 rows; P built directly in A-fragment layout.
__global__ __launch_bounds__(256) void k_attn(
    const int* __restrict__ mask,
    const unsigned short* __restrict__ WhbT,
    const float2* __restrict__ E1F1, const float2* __restrict__ E2F2,
    float* __restrict__ out)
{
    __shared__ unsigned short sB[64 * 136];  // [d][j], padded j-stride 136
    __shared__ float2 sEF[128];

    const int t = threadIdx.x;
    const int bi = blockIdx.x;
    const int ib = bi & 7, hh = (bi >> 3) & 3, b = bi >> 5;
    const int i0 = ib * 128;
    const int b4h = b * 4 + hh;
    const int wid = t >> 6, lane = t & 63;
    const int l15 = lane & 15, q = lane >> 4;
    const int iw = i0 + wid * 32;

    float E1v[2], F1v[2];
#pragma unroll
    for (int mt = 0; mt < 2; ++mt) {
        float2 e = E1F1[(size_t)b4h * 1024 + iw + mt * 16 + l15];
        E1v[mt] = e.x;
        F1v[mt] = e.y;
    }

    floatx4 acc[2][4];
#pragma unroll
    for (int mt = 0; mt < 2; ++mt)
#pragma unroll
        for (int nt = 0; nt < 4; ++nt) {
            floatx4 z = {0.f, 0.f, 0.f, 0.f};
            acc[mt][nt] = z;
        }
    float rs[2] = {0.f, 0.f};

    for (int jt = 0; jt < 8; ++jt) {
        const int j0 = jt * 128;
        // stage Wh^T tile [64 d][128 j] (coalesced: contiguous along j)
#pragma unroll
        for (int p = 0; p < 4; ++p) {
            int c = t + 256 * p;
            int d = c >> 4, jc = c & 15;
            *(int4*)&sB[d * 136 + jc * 8] =
                *(const int4*)&WhbT[((size_t)(b4h * 64 + d)) * 1024 + j0 + jc * 8];
        }
        if (t < 128) sEF[t] = E2F2[(size_t)b4h * 1024 + j0 + t];
        __syncthreads();

#pragma unroll
        for (int ks = 0; ks < 4; ++ks) {
            const int jl = ks * 32 + q * 8;
            float2 ef[8];
#pragma unroll
            for (int jj = 0; jj < 8; ++jj) ef[jj] = sEF[jl + jj];
            short8 bf[4];
#pragma unroll
            for (int nt = 0; nt < 4; ++nt)
                bf[nt] = *(const short8*)&sB[(nt * 16 + l15) * 136 + jl];
#pragma unroll
            for (int mt = 0; mt < 2; ++mt) {
                short8 af;
                float r0 = 0.f;
#pragma unroll
                for (int jj = 0; jj < 8; ++jj) {
                    float w = fmaxf(E1v[mt] * ef[jj].x, F1v[mt] * ef[jj].y);
                    r0 += w;
                    af[jj] = (short)f2b(w);
                }
                rs[mt] += r0;
#pragma unroll
                for (int nt = 0; nt < 4; ++nt)
                    acc[mt][nt] = __builtin_amdgcn_mfma_f32_16x16x32_bf16(af, bf[nt], acc[mt][nt], 0, 0, 0);
            }
        }
        __syncthreads();
    }

    // row-sum l: combine the 4 k-groups (lanes differing in bits 4,5)
#pragma unroll
    for (int mt = 0; mt < 2; ++mt) {
        rs[mt] += __shfl_xor(rs[mt], 16, 64);
        rs[mt] += __shfl_xor(rs[mt], 32, 64);
    }

    // epilogue: C layout row = q*4+r, col = l15; fetch l for C-row via shfl
#pragma unroll
    for (int mt = 0; mt < 2; ++mt)
#pragma unroll
        for (int r = 0; r < 4; ++r) {
            int i = iw + mt * 16 + q * 4 + r;
            float l = __shfl(rs[mt], q * 4 + r, 64);
            int mi = mask[b * 1024 + i];
            float inv = (mi && l > 0.f) ? 1.0f / l : 0.f;
#pragma unroll
            for (int nt = 0; nt < 4; ++nt)
                out[((size_t)(b * 1024 + i)) * 256 + hh * 64 + nt * 16 + l15] =
                    acc[mt][nt][r] * inv;
        }
}

extern "C" void kernel_launch(void* const* d_in, const int* in_sizes, int n_in,
                              void* d_out, int out_size, void* d_ws, size_t ws_size,
                              hipStream_t stream) {
    const float* h = (const float*)d_in[0];
    const int* mask = (const int*)d_in[1];
    const float* W = (const float*)d_in[2];
    const float* a = (const float*)d_in[3];
    float* out = (float*)d_out;

    // ws layout: WhbT bf16 [16][4][64][1024] = 8 MiB; E1F1, E2F2 float2 [16*4*1024]
    unsigned short* WhbT = (unsigned short*)d_ws;
    float2* E1F1 = (float2*)((char*)d_ws + (size_t)16 * 4 * 64 * 1024 * 2);
    float2* E2F2 = E1F1 + 16 * 4 * 1024;

    hipLaunchKernelGGL(k_wh, dim3(512), dim3(256), 0, stream, h, mask, W, a, WhbT, E1F1, E2F2);
    hipLaunchKernelGGL(k_attn, dim3(512), dim3(256), 0, stream, mask, WhbT, E1F1, E2F2, out);
}